// Round 7
// baseline (140.863 us; speedup 1.0000x reference)
//
#include <hip/hip_runtime.h>
#include <math.h>

#define TPB    256
#define PER    8
#define WCH    512          // wave chunk = 64 lanes * PER
#define NCH    2048         // TLEN / WCH
#define TLEN   1048576
#define K1OFF  127          // 65047 / 512
#define LOFF   23           // 65047 % 512
#define NEMA   4            // 0: short/pred, 1: short/targ, 2: long/pred, 3: long/targ
#define CPL    32           // chunks per lane in pass 2 (NCH/64)

// integer power by repeated squaring, deterministic
__device__ __forceinline__ float ipowf(float base, int e) {
    float r = 1.0f, p = base;
    while (e) { if (e & 1) r *= p; p *= p; e >>= 1; }
    return r;
}

// Transposed layout inside a 512-float wave-private window: conflict-free for
// the shifted writes (t%8 const per e, t/8 consecutive in lane -> 2-way = free)
// and the aligned reads (addr = e*64 + lane).
__device__ __forceinline__ int waddr(int t) { return (t & 7) * 64 + (t >> 3); }

__device__ __forceinline__ void load8(const float* __restrict__ p, int lane,
                                      float v[PER]) {
    const float4* p4 = (const float4*)(p + (size_t)lane * PER);
    float4 a = p4[0], b = p4[1];
    v[0] = a.x; v[1] = a.y; v[2] = a.z; v[3] = a.w;
    v[4] = b.x; v[5] = b.y; v[6] = b.z; v[7] = b.w;
}

// Pass 1: wave-per-chunk UNSCALED EMA aggregates (no barriers, no LDS).
// total = sum_lane b_lane * A8^(63-lane).
__global__ __launch_bounds__(TPB, 8) void ldr_partials(
    const float* __restrict__ pred, const float* __restrict__ targ,
    float amS, float amL, float A8S, float A8L,
    float* __restrict__ pB, int rows)
{
    const int j = threadIdx.x, lane = j & 63, w = j >> 6;
    const int k = blockIdx.x * 4 + w, r = blockIdx.y;
    const size_t base = (size_t)r * TLEN + (size_t)k * WCH;
    float xp[PER], xt[PER];
    load8(pred + base, lane, xp);
    load8(targ + base, lane, xt);
    const float wgtS = ipowf(A8S, 63 - lane);
    const float wgtL = ipowf(A8L, 63 - lane);
    float v[NEMA];
    #define SEG(E, XV, AM, WG) {                                              \
        float b = 0.0f;                                                       \
        _Pragma("unroll")                                                     \
        for (int e = 0; e < PER; ++e) b = fmaf(AM, b, XV[e]);                 \
        v[E] = b * WG; }
    SEG(0, xp, amS, wgtS)
    SEG(1, xt, amS, wgtS)
    SEG(2, xp, amL, wgtL)
    SEG(3, xt, amL, wgtL)
    #undef SEG
    #pragma unroll
    for (int E = 0; E < NEMA; ++E) {
        #pragma unroll
        for (int d = 32; d > 0; d >>= 1) v[E] += __shfl_xor(v[E], d, 64);
    }
    if (lane == 0) {
        #pragma unroll
        for (int E = 0; E < NEMA; ++E)
            pB[((size_t)E * rows + r) * NCH + k] = v[E];
    }
}

// Pass 2: carry-in per chunk, IN-PLACE over the aggregates. Chunk coefficient
// Ac = am^512; lane segment coefficient AcW = am^16384.
__global__ __launch_bounds__(64) void ldr_carry(
    float* __restrict__ pB,
    float AcS, float AcSW, float AcL, float AcLW, int rows)
{
    const int g = blockIdx.x;              // e*rows + r
    const int lane = threadIdx.x;
    const bool isShort = g < 2 * rows;
    const float Ac  = isShort ? AcS  : AcL;
    const float AcW = isShort ? AcSW : AcLW;
    float* Bv = pB + (size_t)g * NCH;
    float bm[CPL];
    float B = 0.0f;
    #pragma unroll
    for (int m = 0; m < CPL; ++m) {
        bm[m] = Bv[lane * CPL + m];
        B = fmaf(Ac, B, bm[m]);
    }
    float incl = B, Ad = AcW;
    #pragma unroll
    for (int d = 1; d < 64; d <<= 1) {
        float pb = __shfl_up(incl, d, 64);
        if (lane >= d) incl = fmaf(Ad, pb, incl);
        Ad *= Ad;
    }
    float carry = __shfl_up(incl, 1, 64);
    if (lane == 0) carry = 0.0f;
    #pragma unroll
    for (int m = 0; m < CPL; ++m) {
        Bv[lane * CPL + m] = carry;
        carry = fmaf(Ac, carry, bm[m]);
    }
}

// Pass 3: fused loss, fully wave-autonomous. Each wave owns output chunk k.
// The 48 post-prefix values are PINNED into VGPRs via empty asm so the
// allocator cannot rematerialize/spill them (R6: it chose VGPR=44 and
// re-exposed load latency per phase).
__global__ __launch_bounds__(TPB, 4) void ldr_loss(
    const float* __restrict__ pred, const float* __restrict__ targ,
    const float* __restrict__ cin,
    float amS, float amL, float A8S, float A8L,
    double* __restrict__ acc, int rows)
{
    __shared__ float W[4][WCH];
    __shared__ float rsum[4];
    const int j = threadIdx.x, lane = j & 63, w = j >> 6;
    const int r = blockIdx.y;
    const int k  = blockIdx.x * 4 + w;
    const int k1 = (k + K1OFF) % NCH;
    const int k2 = (k + K1OFF + 1) % NCH;
    const size_t rb = (size_t)r * TLEN;
    float* Wp = &W[w][0];

    float x[6][PER];
    load8(pred + rb + (size_t)k1 * WCH, lane, x[0]);
    load8(targ + rb + (size_t)k1 * WCH, lane, x[1]);
    load8(pred + rb + (size_t)k2 * WCH, lane, x[2]);
    load8(targ + rb + (size_t)k2 * WCH, lane, x[3]);
    load8(pred + rb + (size_t)k  * WCH, lane, x[4]);
    load8(targ + rb + (size_t)k  * WCH, lane, x[5]);
    #define CIN(E, KC) cin[((size_t)(E) * rows + r) * NCH + (KC)]
    float cv[6];
    cv[0] = CIN(2, k1); cv[1] = CIN(3, k1);
    cv[2] = CIN(2, k2); cv[3] = CIN(3, k2);
    cv[4] = CIN(0, k);  cv[5] = CIN(1, k);
    #undef CIN

    // In-place per-lane prefix EMA; then PIN all 48 values into VGPRs.
    #pragma unroll
    for (int s = 0; s < 6; ++s) {
        const float am = (s < 4) ? amL : amS;
        float y = 0.0f;
        #pragma unroll
        for (int e = 0; e < PER; ++e) { y = fmaf(am, y, x[s][e]); x[s][e] = y; }
    }
    #pragma unroll
    for (int s = 0; s < 6; ++s) {
        #pragma unroll
        for (int e = 0; e < PER; ++e) {
            asm volatile("" : "+v"(x[s][e]));
        }
    }

    // 6-wide wave scan with constant multipliers (depth 6, ILP 6)
    float ip[6];
    #pragma unroll
    for (int s = 0; s < 6; ++s) ip[s] = x[s][PER - 1];
    float AdL = A8L, AdS = A8S;
    #pragma unroll
    for (int d = 1; d < 64; d <<= 1) {
        float p[6];
        #pragma unroll
        for (int s = 0; s < 6; ++s) p[s] = __shfl_up(ip[s], d, 64);
        if (lane >= d) {
            ip[0] = fmaf(AdL, p[0], ip[0]);
            ip[1] = fmaf(AdL, p[1], ip[1]);
            ip[2] = fmaf(AdL, p[2], ip[2]);
            ip[3] = fmaf(AdL, p[3], ip[3]);
            ip[4] = fmaf(AdS, p[4], ip[4]);
            ip[5] = fmaf(AdS, p[5], ip[5]);
        }
        AdL *= AdL; AdS *= AdS;
    }
    // y0[s] = EMA state just before this lane's first element
    const float aTL = ipowf(A8L, lane), aTS = ipowf(A8S, lane);
    float y0[6];
    #pragma unroll
    for (int s = 0; s < 6; ++s) {
        float ex = __shfl_up(ip[s], 1, 64);
        if (lane == 0) ex = 0.0f;
        y0[s] = fmaf((s < 4) ? aTL : aTS, cv[s], ex);
    }

    // Window part A: long EMAs of k1, locals >= LOFF -> t = local - LOFF
    {
        float ap = amL;
        #pragma unroll
        for (int e = 0; e < PER; ++e) {
            int t = lane * PER + e - LOFF;
            if (t >= 0) {
                float yp = fmaf(ap, y0[0], x[0][e]);
                float yt = fmaf(ap, y0[1], x[1][e]);
                Wp[waddr(t)] = __fdividef(yt, yp);
            }
            ap *= amL;
        }
    }
    // Window part B: long EMAs of k2, locals < LOFF -> t = local + WCH-LOFF
    {
        float ap = amL;
        #pragma unroll
        for (int e = 0; e < PER; ++e) {
            int l = lane * PER + e;
            if (l < LOFF) {
                float yp = fmaf(ap, y0[2], x[2][e]);
                float yt = fmaf(ap, y0[3], x[3][e]);
                Wp[waddr(l + (WCH - LOFF))] = __fdividef(yt, yp);
            }
            ap *= amL;
        }
    }
    // Same-wave LDS write->read ordering (cross-lane within the wave).
    asm volatile("s_waitcnt lgkmcnt(0)" ::: "memory");

    // Short EMAs of k + loss: |log( (sp/st) * (lt/lp) )|
    float lsum = 0.0f;
    {
        float ap = amS;
        #pragma unroll
        for (int e = 0; e < PER; ++e) {
            float sp = fmaf(ap, y0[4], x[4][e]);
            float st = fmaf(ap, y0[5], x[5][e]);
            float q = __fdividef(sp, st) * Wp[(e << 6) + lane];  // waddr(8*lane+e)
            lsum += fabsf(__logf(q));
            ap *= amS;
        }
    }
    #pragma unroll
    for (int d = 32; d > 0; d >>= 1) lsum += __shfl_xor(lsum, d, 64);
    if (lane == 0) rsum[w] = lsum;
    __syncthreads();
    if (j == 0) atomicAdd(acc, (double)(rsum[0] + rsum[1] + rsum[2] + rsum[3]));
}

__global__ void ldr_finalize(const double* __restrict__ acc,
                             float* __restrict__ out, double inv_n)
{
    out[0] = (float)(acc[0] * inv_n);
}

extern "C" void kernel_launch(void* const* d_in, const int* in_sizes, int n_in,
                              void* d_out, int out_size, void* d_ws, size_t ws_size,
                              hipStream_t stream)
{
    const float* pred = (const float*)d_in[0];
    const float* targ = (const float*)d_in[1];
    const int n = in_sizes[0];
    const int rows = n / TLEN;   // 16

    const double csd = 1.0 - exp(-2200.0 / (50.0 * 44100.0));
    const double cld = 1.0 - exp(-2200.0 / (3000.0 * 44100.0));
    const double amSd = 1.0 - csd, amLd = 1.0 - cld;
    const float amS = (float)amSd, amL = (float)amLd;
    const float A8S  = (float)pow(amSd, 8.0);
    const float A8L  = (float)pow(amLd, 8.0);
    const float AcS  = (float)pow(amSd, 512.0);
    const float AcSW = (float)pow(amSd, 16384.0);
    const float AcL  = (float)pow(amLd, 512.0);
    const float AcLW = (float)pow(amLd, 16384.0);

    // ws layout: [0,8): double acc; [256,...): pB (NEMA*rows*NCH floats,
    // 512 KB), overwritten in-place with carry-ins by ldr_carry.
    char* wsb = (char*)d_ws;
    double* acc = (double*)wsb;
    float* pB  = (float*)(wsb + 256);

    hipMemsetAsync(acc, 0, sizeof(double), stream);

    dim3 grid(NCH / 4, rows);
    ldr_partials<<<grid, TPB, 0, stream>>>(pred, targ, amS, amL,
                                           A8S, A8L, pB, rows);
    ldr_carry<<<NEMA * rows, 64, 0, stream>>>(pB, AcS, AcSW, AcL, AcLW, rows);
    ldr_loss<<<grid, TPB, 0, stream>>>(pred, targ, pB, amS, amL,
                                       A8S, A8L, acc, rows);

    const double inv_n = 1.0 / ((double)rows * (double)TLEN);
    ldr_finalize<<<1, 1, 0, stream>>>(acc, (float*)d_out, inv_n);
}